// Round 13
// baseline (160.667 us; speedup 1.0000x reference)
//
#include <hip/hip_runtime.h>

// GCN layer: out = relu( A0 @ (X W0) + A1 @ (X W1) )
//   X: [65536,128] fp32, W: [128,128] fp32, A*: COO (rows,cols,vals), E=1M each.
//
// Round 13: r12 post-mortem showed sort_gather stuck at ~40% occupancy with
// 1024-thr blocks regardless of grid (r9==r12) -> suspect 1-block/CU cap for
// max-size workgroups. Test: 512-thr blocks (8 waves, up to 4/CU). Also
// partition EPB 8192->4096 (512 blocks, 2/CU) -- it is latency-bound (r11).
// Everything else unchanged from r12.
// Pipeline (4 dispatches): w_swz(+cursor-zero) -> gemm_mfma -> partition
//                          -> sort_gather.

typedef unsigned int   uint;
typedef unsigned short ushort;
typedef unsigned char  uchar;
typedef float f32x4 __attribute__((ext_vector_type(4)));
typedef int   i32x4 __attribute__((ext_vector_type(4)));

constexpr int NBK  = 512;   // buckets: row >> 7 (128 rows each, BN=65536)
constexpr int RPB  = 128;   // rows per bucket
constexpr int EPB  = 4096;  // edges per partition block (chunk ~8 edges)
constexpr int GCAP = 3584;  // global region capacity/bucket (mean+34 sigma)
constexpr int CAP  = 3072;  // LDS sort capacity (mean+22 sigma)

__device__ __forceinline__ ushort f2bf(float f) {      // fp32 -> bf16 RNE
    uint u = __float_as_uint(f);
    u += 0x7fffu + ((u >> 16) & 1u);
    return (ushort)(u >> 16);
}
__device__ __forceinline__ float bf2f(ushort h) {      // bf16 -> fp32 (exact)
    return __uint_as_float((uint)h << 16);
}

// MFMA D-write hazard fence (data-dependent s_nops).
#define ACC_FENCE(a) asm volatile("s_nop 7\n\ts_nop 7" : "+v"(a))

// ---- W pre-swizzle (+ global cursor zeroing in block 64) -----------------
// frag (f,ct,kt): lane l, j=0..7 holds W[f][kt*32+(l>>4)*8+j][ct*16+(l&15)]
__global__ __launch_bounds__(64) void w_swz(const float* __restrict__ W0,
                                            const float* __restrict__ W1,
                                            uint4* __restrict__ Wswz,
                                            int* __restrict__ cur_g) {
    const int bx = blockIdx.x;            // 0..64
    const int l  = threadIdx.x;           // 0..63
    if (bx == 64) {                       // zero 2*NBK cursors
        for (int i = l; i < 2 * NBK; i += 64) cur_g[i] = 0;
        return;
    }
    const int f  = bx >> 5;
    const int ct = (bx >> 2) & 7;
    const int kt = bx & 3;
    const float* W = f ? W1 : W0;
    const int kbase = kt * 32 + (l >> 4) * 8;
    const int col   = ct * 16 + (l & 15);
    ushort h[8];
#pragma unroll
    for (int j = 0; j < 8; ++j)
        h[j] = f2bf(W[(kbase + j) * 128 + col]);
    uint4 o;
    o.x = (uint)h[0] | ((uint)h[1] << 16);
    o.y = (uint)h[2] | ((uint)h[3] << 16);
    o.z = (uint)h[4] | ((uint)h[5] << 16);
    o.w = (uint)h[6] | ((uint)h[7] << 16);
    Wswz[((f * 8 + ct) * 4 + kt) * 64 + l] = o;
}

// ---- MFMA GEMM: H_f = X @ W_f (both filters), bf16 out, split-X accuracy --
__global__ __launch_bounds__(256) void gemm_mfma(const float* __restrict__ X,
                                                 const i32x4* __restrict__ Wswz,
                                                 ushort* __restrict__ H, int BN) {
    __shared__ ushort xs_hi[64][136];     // +8 pad
    __shared__ ushort xs_lo[64][136];
    const int tid = threadIdx.x;
    const int l = tid & 63;
    const int w = tid >> 6;
    const long rbase = (long)blockIdx.x * 64;

    const float4* Xv = reinterpret_cast<const float4*>(X + rbase * 128);
#pragma unroll
    for (int i = 0; i < 8; ++i) {
        int idx = i * 256 + tid;
        int row = idx >> 5, c4 = idx & 31;
        float4 v = Xv[idx];
        ushort4 hi, lo;
        hi.x = f2bf(v.x); lo.x = f2bf(v.x - bf2f(hi.x));
        hi.y = f2bf(v.y); lo.y = f2bf(v.y - bf2f(hi.y));
        hi.z = f2bf(v.z); lo.z = f2bf(v.z - bf2f(hi.z));
        hi.w = f2bf(v.w); lo.w = f2bf(v.w - bf2f(hi.w));
        *reinterpret_cast<ushort4*>(&xs_hi[row][c4 * 4]) = hi;
        *reinterpret_cast<ushort4*>(&xs_lo[row][c4 * 4]) = lo;
    }
    __syncthreads();

    i32x4 a_hi[4], a_lo[4];
    const int arow = w * 16 + (l & 15);
    const int kb = (l >> 4) * 8;
#pragma unroll
    for (int kt = 0; kt < 4; ++kt) {
        a_hi[kt] = *reinterpret_cast<const i32x4*>(&xs_hi[arow][kt * 32 + kb]);
        a_lo[kt] = *reinterpret_cast<const i32x4*>(&xs_lo[arow][kt * 32 + kb]);
    }

    f32x4 acc[2][8];
#pragma unroll
    for (int f = 0; f < 2; ++f)
#pragma unroll
        for (int ct = 0; ct < 8; ++ct)
            acc[f][ct] = (f32x4)0.0f;

#pragma unroll
    for (int ct = 0; ct < 8; ++ct)
#pragma unroll
        for (int f = 0; f < 2; ++f)
#pragma unroll
            for (int kt = 0; kt < 4; ++kt) {
                i32x4 b = Wswz[((f * 8 + ct) * 4 + kt) * 64 + l];
                asm volatile("v_mfma_f32_16x16x32_bf16 %0, %1, %2, %0"
                             : "+v"(acc[f][ct]) : "v"(a_hi[kt]), "v"(b));
                asm volatile("v_mfma_f32_16x16x32_bf16 %0, %1, %2, %0"
                             : "+v"(acc[f][ct]) : "v"(a_lo[kt]), "v"(b));
            }

    // D layout (HW-verified m89/m91): col = l&15, row = (l>>4)*4 + reg
#pragma unroll
    for (int ct = 0; ct < 8; ++ct)
#pragma unroll
        for (int f = 0; f < 2; ++f) {
            f32x4 a = acc[f][ct];
            ACC_FENCE(a);
            ushort* Hf = H + (size_t)f * BN * 128;
            size_t base = (size_t)(rbase + w * 16 + (l >> 4) * 4) * 128
                        + ct * 16 + (l & 15);
            Hf[base]       = f2bf(a.x);
            Hf[base + 128] = f2bf(a.y);
            Hf[base + 256] = f2bf(a.z);
            Hf[base + 384] = f2bf(a.w);
        }
}

// ---- partition into fixed-capacity bucket regions, chunked writes --------
// Region f,b: cvy/cvr[(f*NBK+b)*GCAP .. +GCAP). Block reserves one chunk per
// bucket off the global cursor, then scatters (r5 write-combining lesson;
// 32 B chunks at EPB=4096 -- bounded partial-line cost, traded for 2x blocks).
__global__ __launch_bounds__(512) void partition(const int* __restrict__ r0,
                                                 const int* __restrict__ c0,
                                                 const float* __restrict__ v0,
                                                 const int* __restrict__ r1,
                                                 const int* __restrict__ c1,
                                                 const float* __restrict__ v1,
                                                 int* __restrict__ cur_g,
                                                 uint* __restrict__ cvy,
                                                 uchar* __restrict__ cvr, int E) {
    __shared__ int h[NBK];
    __shared__ int cur[NBK];
    const int f = blockIdx.y, t = threadIdx.x;
    const int*   rows = f ? r1 : r0;
    const int*   cols = f ? c1 : c0;
    const float* vals = f ? v1 : v0;
    const int base = blockIdx.x * EPB;

    h[t] = 0;                              // 512 threads == NBK bins
    __syncthreads();
#pragma unroll
    for (int k = 0; k < EPB / 512; ++k) {
        int e = base + k * 512 + t;
        if (e < E) atomicAdd(&h[rows[e] >> 7], 1);
    }
    __syncthreads();
    cur[t] = atomicAdd(&cur_g[f * NBK + t], h[t]);   // chunk base (region-rel)
    __syncthreads();

#pragma unroll
    for (int k = 0; k < EPB / 512; ++k) {
        int e = base + k * 512 + t;
        if (e < E) {
            int r = rows[e];
            int b = r >> 7;
            int pos = atomicAdd(&cur[b], 1);
            if (pos < GCAP) {              // 34-sigma guard, never taken
                size_t idx = (size_t)(f * NBK + b) * GCAP + pos;
                cvy[idx] = ((uint)cols[e] << 16) | (uint)f2bf(vals[e]);
                cvr[idx] = (uchar)(r & 127);
            }
        }
    }
}

// ---- fused per-bucket LDS sort + gather: out[r] = relu(sum0 + sum1) ------
__device__ __forceinline__ void fma4(float4& a, float v, ushort4 h) {
    a.x = fmaf(v, bf2f(h.x), a.x);
    a.y = fmaf(v, bf2f(h.y), a.y);
    a.z = fmaf(v, bf2f(h.z), a.z);
    a.w = fmaf(v, bf2f(h.w), a.w);
}

__global__ __launch_bounds__(512) void sort_gather(
        const uint* __restrict__ cvy, const uchar* __restrict__ cvr,
        const int* __restrict__ cur_g,
        const ushort* __restrict__ H, int BN,
        float* __restrict__ out) {
    __shared__ uint cvl[2][CAP];          // 24 KB: sorted (col|val) per filter
    __shared__ int rp[2][RPB + 1];        // per-local-row start into cvl
    __shared__ int hcnt[RPB];
    __shared__ int curs[RPB];
    __shared__ int scount[2], sovf[2];

    const int b = blockIdx.x;
    const int t = threadIdx.x;

    // ---- phase 1: sort this bucket's edges by row&127 into LDS ----
#pragma unroll 1
    for (int f = 0; f < 2; ++f) {
        if (t == 0) {
            int n0 = cur_g[f * NBK + b];
            if (n0 > GCAP) n0 = GCAP;     // matches partition's write clamp
            scount[f] = n0;
            sovf[f]   = n0 > CAP;
        }
        if (t < RPB) hcnt[t] = 0;
        __syncthreads();
        const int n = scount[f];
        const uchar* rin = cvr + (size_t)(f * NBK + b) * GCAP;
        const uint*  yin = cvy + (size_t)(f * NBK + b) * GCAP;
        for (int i = t; i < n; i += 512)
            atomicAdd(&hcnt[rin[i]], 1);
        __syncthreads();
        int v = (t < RPB) ? hcnt[t] : 0;
        if (t < RPB) curs[t] = v;
        __syncthreads();
        for (int off = 1; off < RPB; off <<= 1) {     // inclusive Hillis-Steele
            int u = 0;
            if (t < RPB && t >= off) u = curs[t - off];
            __syncthreads();
            if (t < RPB) curs[t] += u;
            __syncthreads();
        }
        if (t < RPB) {
            int ex = curs[t] - v;                     // exclusive base
            rp[f][t] = ex;
            curs[t] = ex;
        }
        if (t == 0) rp[f][RPB] = n;
        __syncthreads();
        if (!sovf[f]) {
            for (int i = t; i < n; i += 512) {
                uchar r = rin[i];
                int pos = atomicAdd(&curs[r], 1);
                cvl[f][pos] = __builtin_nontemporal_load(&yin[i]);
            }
        }
        __syncthreads();
    }

    // ---- phase 2: gather. 16 half-waves x 8 rows each ----
    const int half = t >> 5;              // 0..15
    const int sub  = t & 31;              // float4 column slot
    f32x4* outv = reinterpret_cast<f32x4*>(out);

#pragma unroll 1
    for (int k = 0; k < 8; ++k) {
        const int lr = k * 16 + half;                 // local row 0..127
        const long gr = (long)b * RPB + lr;           // global row

        float4 a0 = make_float4(0.f, 0.f, 0.f, 0.f);
        float4 a1 = make_float4(0.f, 0.f, 0.f, 0.f);
        float4 a2 = make_float4(0.f, 0.f, 0.f, 0.f);
        float4 a3 = make_float4(0.f, 0.f, 0.f, 0.f);

#pragma unroll
        for (int f = 0; f < 2; ++f) {
            const ushort* Hf = H + (size_t)f * BN * 128;
            if (!sovf[f]) {
                int e = rp[f][lr];
                const int e1 = rp[f][lr + 1];
                for (; e + 7 < e1; e += 8) {
                    uint p0 = cvl[f][e],     p1 = cvl[f][e + 1];
                    uint p2 = cvl[f][e + 2], p3 = cvl[f][e + 3];
                    uint p4 = cvl[f][e + 4], p5 = cvl[f][e + 5];
                    uint p6 = cvl[f][e + 6], p7 = cvl[f][e + 7];
                    ushort4 h0 = reinterpret_cast<const ushort4*>(Hf + (size_t)(p0 >> 16) * 128)[sub];
                    ushort4 h1 = reinterpret_cast<const ushort4*>(Hf + (size_t)(p1 >> 16) * 128)[sub];
                    ushort4 h2 = reinterpret_cast<const ushort4*>(Hf + (size_t)(p2 >> 16) * 128)[sub];
                    ushort4 h3 = reinterpret_cast<const ushort4*>(Hf + (size_t)(p3 >> 16) * 128)[sub];
                    ushort4 h4 = reinterpret_cast<const ushort4*>(Hf + (size_t)(p4 >> 16) * 128)[sub];
                    ushort4 h5 = reinterpret_cast<const ushort4*>(Hf + (size_t)(p5 >> 16) * 128)[sub];
                    ushort4 h6 = reinterpret_cast<const ushort4*>(Hf + (size_t)(p6 >> 16) * 128)[sub];
                    ushort4 h7 = reinterpret_cast<const ushort4*>(Hf + (size_t)(p7 >> 16) * 128)[sub];
                    fma4(a0, __uint_as_float(p0 << 16), h0);
                    fma4(a1, __uint_as_float(p1 << 16), h1);
                    fma4(a2, __uint_as_float(p2 << 16), h2);
                    fma4(a3, __uint_as_float(p3 << 16), h3);
                    fma4(a0, __uint_as_float(p4 << 16), h4);
                    fma4(a1, __uint_as_float(p5 << 16), h5);
                    fma4(a2, __uint_as_float(p6 << 16), h6);
                    fma4(a3, __uint_as_float(p7 << 16), h7);
                }
                for (; e + 3 < e1; e += 4) {
                    uint p0 = cvl[f][e],     p1 = cvl[f][e + 1];
                    uint p2 = cvl[f][e + 2], p3 = cvl[f][e + 3];
                    ushort4 h0 = reinterpret_cast<const ushort4*>(Hf + (size_t)(p0 >> 16) * 128)[sub];
                    ushort4 h1 = reinterpret_cast<const ushort4*>(Hf + (size_t)(p1 >> 16) * 128)[sub];
                    ushort4 h2 = reinterpret_cast<const ushort4*>(Hf + (size_t)(p2 >> 16) * 128)[sub];
                    ushort4 h3 = reinterpret_cast<const ushort4*>(Hf + (size_t)(p3 >> 16) * 128)[sub];
                    fma4(a0, __uint_as_float(p0 << 16), h0);
                    fma4(a1, __uint_as_float(p1 << 16), h1);
                    fma4(a2, __uint_as_float(p2 << 16), h2);
                    fma4(a3, __uint_as_float(p3 << 16), h3);
                }
                for (; e < e1; ++e) {
                    uint p0 = cvl[f][e];
                    ushort4 h0 = reinterpret_cast<const ushort4*>(Hf + (size_t)(p0 >> 16) * 128)[sub];
                    fma4(a0, __uint_as_float(p0 << 16), h0);
                }
            } else {
                // never-taken safety path (bucket > CAP): scan region
                const int n = scount[f];
                const uchar* rin = cvr + (size_t)(f * NBK + b) * GCAP;
                const uint*  yin = cvy + (size_t)(f * NBK + b) * GCAP;
                for (int i = 0; i < n; ++i) {
                    if (rin[i] == (uchar)lr) {
                        uint p0 = yin[i];
                        ushort4 h0 = reinterpret_cast<const ushort4*>(Hf + (size_t)(p0 >> 16) * 128)[sub];
                        fma4(a0, __uint_as_float(p0 << 16), h0);
                    }
                }
            }
        }

        f32x4 o;
        o.x = fmaxf((a0.x + a1.x) + (a2.x + a3.x), 0.0f);
        o.y = fmaxf((a0.y + a1.y) + (a2.y + a3.y), 0.0f);
        o.z = fmaxf((a0.z + a1.z) + (a2.z + a3.z), 0.0f);
        o.w = fmaxf((a0.w + a1.w) + (a2.w + a3.w), 0.0f);
        __builtin_nontemporal_store(o, outv + gr * 32 + sub);
    }
}

extern "C" void kernel_launch(void* const* d_in, const int* in_sizes, int n_in,
                              void* d_out, int out_size, void* d_ws, size_t ws_size,
                              hipStream_t stream) {
    const float* X     = (const float*)d_in[0];
    const float* W0    = (const float*)d_in[1];
    const float* W1    = (const float*)d_in[2];
    const int*   rows0 = (const int*)d_in[3];
    const int*   cols0 = (const int*)d_in[4];
    const float* vals0 = (const float*)d_in[5];
    const int*   rows1 = (const int*)d_in[6];
    const int*   cols1 = (const int*)d_in[7];
    const float* vals1 = (const float*)d_in[8];
    float* out = (float*)d_out;

    const int BN = in_sizes[0] / 128;               // 65536
    const int E  = in_sizes[3];                     // 1048576
    const int partb = (E + EPB - 1) / EPB;          // 256

    // Workspace (~51.9 MB; >= ~54.4 MB proven available in round 8):
    char* ws = (char*)d_ws;
    size_t off = 0;
    auto alloc = [&](size_t bytes) {
        void* p = ws + off;
        off = (off + bytes + 255) & ~(size_t)255;
        return p;
    };
    ushort* H     = (ushort*)alloc((size_t)2 * BN * 128 * sizeof(ushort));   // 32 MiB
    uint4*  Wswz  = (uint4*) alloc((size_t)2 * 128 * 128 * sizeof(ushort));  // 128 KiB
    uint*   cvy   = (uint*)  alloc((size_t)2 * NBK * GCAP * sizeof(uint));   // 14.7 MiB
    uchar*  cvr   = (uchar*) alloc((size_t)2 * NBK * GCAP * sizeof(uchar));  // 3.7 MiB
    int*    cur_g = (int*)   alloc((size_t)2 * NBK * sizeof(int));           // 4 KiB

    w_swz<<<65, 64, 0, stream>>>(W0, W1, Wswz, cur_g);
    gemm_mfma<<<BN / 64, 256, 0, stream>>>(X, (const i32x4*)Wswz, H, BN);
    partition<<<dim3(partb, 2), 512, 0, stream>>>(rows0, cols0, vals0,
                                                  rows1, cols1, vals1,
                                                  cur_g, cvy, cvr, E);
    sort_gather<<<NBK, 512, 0, stream>>>(cvy, cvr, cur_g, H, BN, out);
}

// Round 14
// 147.812 us; speedup vs baseline: 1.0870x; 1.0870x over previous
//
#include <hip/hip_runtime.h>

// GCN layer: out = relu( A0 @ (X W0) + A1 @ (X W1) )
//   X: [65536,128] fp32, W: [128,128] fp32, A*: COO (rows,cols,vals), E=1M each.
//
// Round 14: gather is proven throughput-bound on the L2-miss path (~2.9 TB/s
// for random 256B granules; flat across 4 independent levers) -> frozen at
// its 82 us floor. Partition reverted to EPB=8192 (64B chunks -- r13's 32B
// chunks cost +8 us partial-line amplification) but widened to 1024 threads
// (16 waves/CU vs 8; latency-bound per r11). sort_gather kept at 512 thr
// (r13, marginally fastest). Pipeline floor = sum of serial dispatches.
// Pipeline (4): w_swz(+cursor-zero) -> gemm_mfma -> partition -> sort_gather.

typedef unsigned int   uint;
typedef unsigned short ushort;
typedef unsigned char  uchar;
typedef float f32x4 __attribute__((ext_vector_type(4)));
typedef int   i32x4 __attribute__((ext_vector_type(4)));

constexpr int NBK  = 512;   // buckets: row >> 7 (128 rows each, BN=65536)
constexpr int RPB  = 128;   // rows per bucket
constexpr int EPB  = 8192;  // edges per partition block (chunk ~16 edges = 64B)
constexpr int GCAP = 3584;  // global region capacity/bucket (mean+34 sigma)
constexpr int CAP  = 3072;  // LDS sort capacity (mean+22 sigma)

__device__ __forceinline__ ushort f2bf(float f) {      // fp32 -> bf16 RNE
    uint u = __float_as_uint(f);
    u += 0x7fffu + ((u >> 16) & 1u);
    return (ushort)(u >> 16);
}
__device__ __forceinline__ float bf2f(ushort h) {      // bf16 -> fp32 (exact)
    return __uint_as_float((uint)h << 16);
}

// MFMA D-write hazard fence (data-dependent s_nops).
#define ACC_FENCE(a) asm volatile("s_nop 7\n\ts_nop 7" : "+v"(a))

// ---- W pre-swizzle (+ global cursor zeroing in block 64) -----------------
// frag (f,ct,kt): lane l, j=0..7 holds W[f][kt*32+(l>>4)*8+j][ct*16+(l&15)]
__global__ __launch_bounds__(64) void w_swz(const float* __restrict__ W0,
                                            const float* __restrict__ W1,
                                            uint4* __restrict__ Wswz,
                                            int* __restrict__ cur_g) {
    const int bx = blockIdx.x;            // 0..64
    const int l  = threadIdx.x;           // 0..63
    if (bx == 64) {                       // zero 2*NBK cursors
        for (int i = l; i < 2 * NBK; i += 64) cur_g[i] = 0;
        return;
    }
    const int f  = bx >> 5;
    const int ct = (bx >> 2) & 7;
    const int kt = bx & 3;
    const float* W = f ? W1 : W0;
    const int kbase = kt * 32 + (l >> 4) * 8;
    const int col   = ct * 16 + (l & 15);
    ushort h[8];
#pragma unroll
    for (int j = 0; j < 8; ++j)
        h[j] = f2bf(W[(kbase + j) * 128 + col]);
    uint4 o;
    o.x = (uint)h[0] | ((uint)h[1] << 16);
    o.y = (uint)h[2] | ((uint)h[3] << 16);
    o.z = (uint)h[4] | ((uint)h[5] << 16);
    o.w = (uint)h[6] | ((uint)h[7] << 16);
    Wswz[((f * 8 + ct) * 4 + kt) * 64 + l] = o;
}

// ---- MFMA GEMM: H_f = X @ W_f (both filters), bf16 out, split-X accuracy --
__global__ __launch_bounds__(256) void gemm_mfma(const float* __restrict__ X,
                                                 const i32x4* __restrict__ Wswz,
                                                 ushort* __restrict__ H, int BN) {
    __shared__ ushort xs_hi[64][136];     // +8 pad
    __shared__ ushort xs_lo[64][136];
    const int tid = threadIdx.x;
    const int l = tid & 63;
    const int w = tid >> 6;
    const long rbase = (long)blockIdx.x * 64;

    const float4* Xv = reinterpret_cast<const float4*>(X + rbase * 128);
#pragma unroll
    for (int i = 0; i < 8; ++i) {
        int idx = i * 256 + tid;
        int row = idx >> 5, c4 = idx & 31;
        float4 v = Xv[idx];
        ushort4 hi, lo;
        hi.x = f2bf(v.x); lo.x = f2bf(v.x - bf2f(hi.x));
        hi.y = f2bf(v.y); lo.y = f2bf(v.y - bf2f(hi.y));
        hi.z = f2bf(v.z); lo.z = f2bf(v.z - bf2f(hi.z));
        hi.w = f2bf(v.w); lo.w = f2bf(v.w - bf2f(hi.w));
        *reinterpret_cast<ushort4*>(&xs_hi[row][c4 * 4]) = hi;
        *reinterpret_cast<ushort4*>(&xs_lo[row][c4 * 4]) = lo;
    }
    __syncthreads();

    i32x4 a_hi[4], a_lo[4];
    const int arow = w * 16 + (l & 15);
    const int kb = (l >> 4) * 8;
#pragma unroll
    for (int kt = 0; kt < 4; ++kt) {
        a_hi[kt] = *reinterpret_cast<const i32x4*>(&xs_hi[arow][kt * 32 + kb]);
        a_lo[kt] = *reinterpret_cast<const i32x4*>(&xs_lo[arow][kt * 32 + kb]);
    }

    f32x4 acc[2][8];
#pragma unroll
    for (int f = 0; f < 2; ++f)
#pragma unroll
        for (int ct = 0; ct < 8; ++ct)
            acc[f][ct] = (f32x4)0.0f;

#pragma unroll
    for (int ct = 0; ct < 8; ++ct)
#pragma unroll
        for (int f = 0; f < 2; ++f)
#pragma unroll
            for (int kt = 0; kt < 4; ++kt) {
                i32x4 b = Wswz[((f * 8 + ct) * 4 + kt) * 64 + l];
                asm volatile("v_mfma_f32_16x16x32_bf16 %0, %1, %2, %0"
                             : "+v"(acc[f][ct]) : "v"(a_hi[kt]), "v"(b));
                asm volatile("v_mfma_f32_16x16x32_bf16 %0, %1, %2, %0"
                             : "+v"(acc[f][ct]) : "v"(a_lo[kt]), "v"(b));
            }

    // D layout (HW-verified m89/m91): col = l&15, row = (l>>4)*4 + reg
#pragma unroll
    for (int ct = 0; ct < 8; ++ct)
#pragma unroll
        for (int f = 0; f < 2; ++f) {
            f32x4 a = acc[f][ct];
            ACC_FENCE(a);
            ushort* Hf = H + (size_t)f * BN * 128;
            size_t base = (size_t)(rbase + w * 16 + (l >> 4) * 4) * 128
                        + ct * 16 + (l & 15);
            Hf[base]       = f2bf(a.x);
            Hf[base + 128] = f2bf(a.y);
            Hf[base + 256] = f2bf(a.z);
            Hf[base + 384] = f2bf(a.w);
        }
}

// ---- partition into fixed-capacity bucket regions, chunked writes --------
// Region f,b: cvy/cvr[(f*NBK+b)*GCAP .. +GCAP). Block reserves one chunk per
// bucket off the global cursor, then scatters -- same-line writers are
// same-block (r5 write-combining lesson; 64B chunks at EPB=8192).
// 1024 threads: 16 waves/CU (latency-bound kernel, r11/r13 evidence).
__global__ __launch_bounds__(1024) void partition(const int* __restrict__ r0,
                                                  const int* __restrict__ c0,
                                                  const float* __restrict__ v0,
                                                  const int* __restrict__ r1,
                                                  const int* __restrict__ c1,
                                                  const float* __restrict__ v1,
                                                  int* __restrict__ cur_g,
                                                  uint* __restrict__ cvy,
                                                  uchar* __restrict__ cvr, int E) {
    __shared__ int h[NBK];
    __shared__ int cur[NBK];
    const int f = blockIdx.y, t = threadIdx.x;
    const int*   rows = f ? r1 : r0;
    const int*   cols = f ? c1 : c0;
    const float* vals = f ? v1 : v0;
    const int base = blockIdx.x * EPB;

    if (t < NBK) h[t] = 0;
    __syncthreads();
#pragma unroll
    for (int k = 0; k < EPB / 1024; ++k) {
        int e = base + k * 1024 + t;
        if (e < E) atomicAdd(&h[rows[e] >> 7], 1);
    }
    __syncthreads();
    if (t < NBK)
        cur[t] = atomicAdd(&cur_g[f * NBK + t], h[t]);  // chunk base (region-rel)
    __syncthreads();

#pragma unroll
    for (int k = 0; k < EPB / 1024; ++k) {
        int e = base + k * 1024 + t;
        if (e < E) {
            int r = rows[e];
            int b = r >> 7;
            int pos = atomicAdd(&cur[b], 1);
            if (pos < GCAP) {              // 34-sigma guard, never taken
                size_t idx = (size_t)(f * NBK + b) * GCAP + pos;
                cvy[idx] = ((uint)cols[e] << 16) | (uint)f2bf(vals[e]);
                cvr[idx] = (uchar)(r & 127);
            }
        }
    }
}

// ---- fused per-bucket LDS sort + gather: out[r] = relu(sum0 + sum1) ------
__device__ __forceinline__ void fma4(float4& a, float v, ushort4 h) {
    a.x = fmaf(v, bf2f(h.x), a.x);
    a.y = fmaf(v, bf2f(h.y), a.y);
    a.z = fmaf(v, bf2f(h.z), a.z);
    a.w = fmaf(v, bf2f(h.w), a.w);
}

__global__ __launch_bounds__(512) void sort_gather(
        const uint* __restrict__ cvy, const uchar* __restrict__ cvr,
        const int* __restrict__ cur_g,
        const ushort* __restrict__ H, int BN,
        float* __restrict__ out) {
    __shared__ uint cvl[2][CAP];          // 24 KB: sorted (col|val) per filter
    __shared__ int rp[2][RPB + 1];        // per-local-row start into cvl
    __shared__ int hcnt[RPB];
    __shared__ int curs[RPB];
    __shared__ int scount[2], sovf[2];

    const int b = blockIdx.x;
    const int t = threadIdx.x;

    // ---- phase 1: sort this bucket's edges by row&127 into LDS ----
#pragma unroll 1
    for (int f = 0; f < 2; ++f) {
        if (t == 0) {
            int n0 = cur_g[f * NBK + b];
            if (n0 > GCAP) n0 = GCAP;     // matches partition's write clamp
            scount[f] = n0;
            sovf[f]   = n0 > CAP;
        }
        if (t < RPB) hcnt[t] = 0;
        __syncthreads();
        const int n = scount[f];
        const uchar* rin = cvr + (size_t)(f * NBK + b) * GCAP;
        const uint*  yin = cvy + (size_t)(f * NBK + b) * GCAP;
        for (int i = t; i < n; i += 512)
            atomicAdd(&hcnt[rin[i]], 1);
        __syncthreads();
        int v = (t < RPB) ? hcnt[t] : 0;
        if (t < RPB) curs[t] = v;
        __syncthreads();
        for (int off = 1; off < RPB; off <<= 1) {     // inclusive Hillis-Steele
            int u = 0;
            if (t < RPB && t >= off) u = curs[t - off];
            __syncthreads();
            if (t < RPB) curs[t] += u;
            __syncthreads();
        }
        if (t < RPB) {
            int ex = curs[t] - v;                     // exclusive base
            rp[f][t] = ex;
            curs[t] = ex;
        }
        if (t == 0) rp[f][RPB] = n;
        __syncthreads();
        if (!sovf[f]) {
            for (int i = t; i < n; i += 512) {
                uchar r = rin[i];
                int pos = atomicAdd(&curs[r], 1);
                cvl[f][pos] = __builtin_nontemporal_load(&yin[i]);
            }
        }
        __syncthreads();
    }

    // ---- phase 2: gather. 16 half-waves x 8 rows each ----
    const int half = t >> 5;              // 0..15
    const int sub  = t & 31;              // float4 column slot
    f32x4* outv = reinterpret_cast<f32x4*>(out);

#pragma unroll 1
    for (int k = 0; k < 8; ++k) {
        const int lr = k * 16 + half;                 // local row 0..127
        const long gr = (long)b * RPB + lr;           // global row

        float4 a0 = make_float4(0.f, 0.f, 0.f, 0.f);
        float4 a1 = make_float4(0.f, 0.f, 0.f, 0.f);
        float4 a2 = make_float4(0.f, 0.f, 0.f, 0.f);
        float4 a3 = make_float4(0.f, 0.f, 0.f, 0.f);

#pragma unroll
        for (int f = 0; f < 2; ++f) {
            const ushort* Hf = H + (size_t)f * BN * 128;
            if (!sovf[f]) {
                int e = rp[f][lr];
                const int e1 = rp[f][lr + 1];
                for (; e + 7 < e1; e += 8) {
                    uint p0 = cvl[f][e],     p1 = cvl[f][e + 1];
                    uint p2 = cvl[f][e + 2], p3 = cvl[f][e + 3];
                    uint p4 = cvl[f][e + 4], p5 = cvl[f][e + 5];
                    uint p6 = cvl[f][e + 6], p7 = cvl[f][e + 7];
                    ushort4 h0 = reinterpret_cast<const ushort4*>(Hf + (size_t)(p0 >> 16) * 128)[sub];
                    ushort4 h1 = reinterpret_cast<const ushort4*>(Hf + (size_t)(p1 >> 16) * 128)[sub];
                    ushort4 h2 = reinterpret_cast<const ushort4*>(Hf + (size_t)(p2 >> 16) * 128)[sub];
                    ushort4 h3 = reinterpret_cast<const ushort4*>(Hf + (size_t)(p3 >> 16) * 128)[sub];
                    ushort4 h4 = reinterpret_cast<const ushort4*>(Hf + (size_t)(p4 >> 16) * 128)[sub];
                    ushort4 h5 = reinterpret_cast<const ushort4*>(Hf + (size_t)(p5 >> 16) * 128)[sub];
                    ushort4 h6 = reinterpret_cast<const ushort4*>(Hf + (size_t)(p6 >> 16) * 128)[sub];
                    ushort4 h7 = reinterpret_cast<const ushort4*>(Hf + (size_t)(p7 >> 16) * 128)[sub];
                    fma4(a0, __uint_as_float(p0 << 16), h0);
                    fma4(a1, __uint_as_float(p1 << 16), h1);
                    fma4(a2, __uint_as_float(p2 << 16), h2);
                    fma4(a3, __uint_as_float(p3 << 16), h3);
                    fma4(a0, __uint_as_float(p4 << 16), h4);
                    fma4(a1, __uint_as_float(p5 << 16), h5);
                    fma4(a2, __uint_as_float(p6 << 16), h6);
                    fma4(a3, __uint_as_float(p7 << 16), h7);
                }
                for (; e + 3 < e1; e += 4) {
                    uint p0 = cvl[f][e],     p1 = cvl[f][e + 1];
                    uint p2 = cvl[f][e + 2], p3 = cvl[f][e + 3];
                    ushort4 h0 = reinterpret_cast<const ushort4*>(Hf + (size_t)(p0 >> 16) * 128)[sub];
                    ushort4 h1 = reinterpret_cast<const ushort4*>(Hf + (size_t)(p1 >> 16) * 128)[sub];
                    ushort4 h2 = reinterpret_cast<const ushort4*>(Hf + (size_t)(p2 >> 16) * 128)[sub];
                    ushort4 h3 = reinterpret_cast<const ushort4*>(Hf + (size_t)(p3 >> 16) * 128)[sub];
                    fma4(a0, __uint_as_float(p0 << 16), h0);
                    fma4(a1, __uint_as_float(p1 << 16), h1);
                    fma4(a2, __uint_as_float(p2 << 16), h2);
                    fma4(a3, __uint_as_float(p3 << 16), h3);
                }
                for (; e < e1; ++e) {
                    uint p0 = cvl[f][e];
                    ushort4 h0 = reinterpret_cast<const ushort4*>(Hf + (size_t)(p0 >> 16) * 128)[sub];
                    fma4(a0, __uint_as_float(p0 << 16), h0);
                }
            } else {
                // never-taken safety path (bucket > CAP): scan region
                const int n = scount[f];
                const uchar* rin = cvr + (size_t)(f * NBK + b) * GCAP;
                const uint*  yin = cvy + (size_t)(f * NBK + b) * GCAP;
                for (int i = 0; i < n; ++i) {
                    if (rin[i] == (uchar)lr) {
                        uint p0 = yin[i];
                        ushort4 h0 = reinterpret_cast<const ushort4*>(Hf + (size_t)(p0 >> 16) * 128)[sub];
                        fma4(a0, __uint_as_float(p0 << 16), h0);
                    }
                }
            }
        }

        f32x4 o;
        o.x = fmaxf((a0.x + a1.x) + (a2.x + a3.x), 0.0f);
        o.y = fmaxf((a0.y + a1.y) + (a2.y + a3.y), 0.0f);
        o.z = fmaxf((a0.z + a1.z) + (a2.z + a3.z), 0.0f);
        o.w = fmaxf((a0.w + a1.w) + (a2.w + a3.w), 0.0f);
        __builtin_nontemporal_store(o, outv + gr * 32 + sub);
    }
}

extern "C" void kernel_launch(void* const* d_in, const int* in_sizes, int n_in,
                              void* d_out, int out_size, void* d_ws, size_t ws_size,
                              hipStream_t stream) {
    const float* X     = (const float*)d_in[0];
    const float* W0    = (const float*)d_in[1];
    const float* W1    = (const float*)d_in[2];
    const int*   rows0 = (const int*)d_in[3];
    const int*   cols0 = (const int*)d_in[4];
    const float* vals0 = (const float*)d_in[5];
    const int*   rows1 = (const int*)d_in[6];
    const int*   cols1 = (const int*)d_in[7];
    const float* vals1 = (const float*)d_in[8];
    float* out = (float*)d_out;

    const int BN = in_sizes[0] / 128;               // 65536
    const int E  = in_sizes[3];                     // 1048576
    const int partb = (E + EPB - 1) / EPB;          // 128

    // Workspace (~51.9 MB; >= ~54.4 MB proven available in round 8):
    char* ws = (char*)d_ws;
    size_t off = 0;
    auto alloc = [&](size_t bytes) {
        void* p = ws + off;
        off = (off + bytes + 255) & ~(size_t)255;
        return p;
    };
    ushort* H     = (ushort*)alloc((size_t)2 * BN * 128 * sizeof(ushort));   // 32 MiB
    uint4*  Wswz  = (uint4*) alloc((size_t)2 * 128 * 128 * sizeof(ushort));  // 128 KiB
    uint*   cvy   = (uint*)  alloc((size_t)2 * NBK * GCAP * sizeof(uint));   // 14.7 MiB
    uchar*  cvr   = (uchar*) alloc((size_t)2 * NBK * GCAP * sizeof(uchar));  // 3.7 MiB
    int*    cur_g = (int*)   alloc((size_t)2 * NBK * sizeof(int));           // 4 KiB

    w_swz<<<65, 64, 0, stream>>>(W0, W1, Wswz, cur_g);
    gemm_mfma<<<BN / 64, 256, 0, stream>>>(X, (const i32x4*)Wswz, H, BN);
    partition<<<dim3(partb, 2), 1024, 0, stream>>>(rows0, cols0, vals0,
                                                   rows1, cols1, vals1,
                                                   cur_g, cvy, cvr, E);
    sort_gather<<<NBK, 512, 0, stream>>>(cvy, cvr, cur_g, H, BN, out);
}

// Round 15
// 144.626 us; speedup vs baseline: 1.1109x; 1.0220x over previous
//
#include <hip/hip_runtime.h>

// GCN layer: out = relu( A0 @ (X W0) + A1 @ (X W1) )
//   X: [65536,128] fp32, W: [128,128] fp32, A*: COO (rows,cols,vals), E=1M each.
//
// Round 15: gather frozen at its 82.5 us / 235.6 MB L2-miss floor (flat
// across 5 levers). Remaining cost is serial gemm + partition + gaps.
// Fix: fuse them into ONE kernel (they're independent). r8's fusion failure
// mechanism was the 34.8 KB gemm LDS allocated for every block -> this
// round gemm is LDS-FREE (A-fragments loaded straight from global X with
// in-register hi/lo split; fragment k-mapping unchanged), so the fused
// kernel allocates only partition's 4 KB. Partition blocks launch first
// (bx < 2*partb) and overlap gemm's MFMA phase.
// Pipeline (3 dispatches): w_swz(+cursor-zero) -> gemm_part -> sort_gather.

typedef unsigned int   uint;
typedef unsigned short ushort;
typedef unsigned char  uchar;
typedef float f32x4 __attribute__((ext_vector_type(4)));
typedef int   i32x4 __attribute__((ext_vector_type(4)));

constexpr int NBK  = 512;   // buckets: row >> 7 (128 rows each, BN=65536)
constexpr int RPB  = 128;   // rows per bucket
constexpr int EPB  = 8192;  // edges per partition block (chunk ~16 edges = 64B)
constexpr int GCAP = 3584;  // global region capacity/bucket (mean+34 sigma)
constexpr int CAP  = 3072;  // LDS sort capacity (mean+22 sigma)

__device__ __forceinline__ ushort f2bf(float f) {      // fp32 -> bf16 RNE
    uint u = __float_as_uint(f);
    u += 0x7fffu + ((u >> 16) & 1u);
    return (ushort)(u >> 16);
}
__device__ __forceinline__ float bf2f(ushort h) {      // bf16 -> fp32 (exact)
    return __uint_as_float((uint)h << 16);
}

// MFMA D-write hazard fence (data-dependent s_nops).
#define ACC_FENCE(a) asm volatile("s_nop 7\n\ts_nop 7" : "+v"(a))

// ---- W pre-swizzle (+ global cursor zeroing in block 64) -----------------
// frag (f,ct,kt): lane l, j=0..7 holds W[f][kt*32+(l>>4)*8+j][ct*16+(l&15)]
__global__ __launch_bounds__(64) void w_swz(const float* __restrict__ W0,
                                            const float* __restrict__ W1,
                                            uint4* __restrict__ Wswz,
                                            int* __restrict__ cur_g) {
    const int bx = blockIdx.x;            // 0..64
    const int l  = threadIdx.x;           // 0..63
    if (bx == 64) {                       // zero 2*NBK cursors
        for (int i = l; i < 2 * NBK; i += 64) cur_g[i] = 0;
        return;
    }
    const int f  = bx >> 5;
    const int ct = (bx >> 2) & 7;
    const int kt = bx & 3;
    const float* W = f ? W1 : W0;
    const int kbase = kt * 32 + (l >> 4) * 8;
    const int col   = ct * 16 + (l & 15);
    ushort h[8];
#pragma unroll
    for (int j = 0; j < 8; ++j)
        h[j] = f2bf(W[(kbase + j) * 128 + col]);
    uint4 o;
    o.x = (uint)h[0] | ((uint)h[1] << 16);
    o.y = (uint)h[2] | ((uint)h[3] << 16);
    o.z = (uint)h[4] | ((uint)h[5] << 16);
    o.w = (uint)h[6] | ((uint)h[7] << 16);
    Wswz[((f * 8 + ct) * 4 + kt) * 64 + l] = o;
}

// ---- fused: partition (bx < 2*partb) || LDS-free MFMA GEMM ---------------
__device__ __forceinline__ uint pack2bf(float a, float b) {
    return (uint)f2bf(a) | ((uint)f2bf(b) << 16);
}

__global__ __launch_bounds__(256) void gemm_part(
        const float* __restrict__ X, const i32x4* __restrict__ Wswz,
        ushort* __restrict__ H, int BN,
        const int* __restrict__ r0, const int* __restrict__ c0,
        const float* __restrict__ v0,
        const int* __restrict__ r1, const int* __restrict__ c1,
        const float* __restrict__ v1,
        int* __restrict__ cur_g, uint* __restrict__ cvy,
        uchar* __restrict__ cvr, int E, int partb) {
    __shared__ int h[NBK];                // 4 KB total -- the only LDS
    __shared__ int cur[NBK];
    const int bx = blockIdx.x;
    const int t  = threadIdx.x;

    if (bx < 2 * partb) {
        // ---- partition branch: bucket-region counting scatter ----
        const int f  = bx / partb;
        const int px = bx % partb;
        const int*   rows = f ? r1 : r0;
        const int*   cols = f ? c1 : c0;
        const float* vals = f ? v1 : v0;
        const int base = px * EPB;

        h[t] = 0; h[t + 256] = 0;
        __syncthreads();
#pragma unroll 1
        for (int k = 0; k < EPB / 256; ++k) {
            int e = base + k * 256 + t;
            if (e < E) atomicAdd(&h[rows[e] >> 7], 1);
        }
        __syncthreads();
        cur[t]       = atomicAdd(&cur_g[f * NBK + t],       h[t]);
        cur[t + 256] = atomicAdd(&cur_g[f * NBK + t + 256], h[t + 256]);
        __syncthreads();

#pragma unroll 1
        for (int k = 0; k < EPB / 256; ++k) {
            int e = base + k * 256 + t;
            if (e < E) {
                int r = rows[e];
                int b = r >> 7;
                int pos = atomicAdd(&cur[b], 1);
                if (pos < GCAP) {          // 34-sigma guard, never taken
                    size_t idx = (size_t)(f * NBK + b) * GCAP + pos;
                    cvy[idx] = ((uint)cols[e] << 16) | (uint)f2bf(vals[e]);
                    cvr[idx] = (uchar)(r & 127);
                }
            }
        }
        return;
    }

    // ---- LDS-free MFMA GEMM: H_f = X @ W_f (both filters), split-X ----
    const int gx = bx - 2 * partb;
    const int l = t & 63;
    const int w = t >> 6;                 // wave 0..3 -> rows w*16..+16
    const long rbase = (long)gx * 64;
    const int arow = w * 16 + (l & 15);
    const int kb = (l >> 4) * 8;

    // A-fragments straight from global (same k-mapping as the LDS version):
    // lane l, kt: X[rbase+arow][kt*32 + kb .. +8]
    const float* Xr = X + (rbase + arow) * 128;
    i32x4 a_hi[4], a_lo[4];
#pragma unroll
    for (int kt = 0; kt < 4; ++kt) {
        float4 u0 = *reinterpret_cast<const float4*>(Xr + kt * 32 + kb);
        float4 u1 = *reinterpret_cast<const float4*>(Xr + kt * 32 + kb + 4);
        float e0, e1;
        i32x4 hi, lo;
        hi.x = (int)pack2bf(u0.x, u0.y);
        e0 = u0.x - bf2f(f2bf(u0.x)); e1 = u0.y - bf2f(f2bf(u0.y));
        lo.x = (int)pack2bf(e0, e1);
        hi.y = (int)pack2bf(u0.z, u0.w);
        e0 = u0.z - bf2f(f2bf(u0.z)); e1 = u0.w - bf2f(f2bf(u0.w));
        lo.y = (int)pack2bf(e0, e1);
        hi.z = (int)pack2bf(u1.x, u1.y);
        e0 = u1.x - bf2f(f2bf(u1.x)); e1 = u1.y - bf2f(f2bf(u1.y));
        lo.z = (int)pack2bf(e0, e1);
        hi.w = (int)pack2bf(u1.z, u1.w);
        e0 = u1.z - bf2f(f2bf(u1.z)); e1 = u1.w - bf2f(f2bf(u1.w));
        lo.w = (int)pack2bf(e0, e1);
        a_hi[kt] = hi;
        a_lo[kt] = lo;
    }

    f32x4 acc[2][8];
#pragma unroll
    for (int f = 0; f < 2; ++f)
#pragma unroll
        for (int ct = 0; ct < 8; ++ct)
            acc[f][ct] = (f32x4)0.0f;

#pragma unroll
    for (int ct = 0; ct < 8; ++ct)
#pragma unroll
        for (int f = 0; f < 2; ++f)
#pragma unroll
            for (int kt = 0; kt < 4; ++kt) {
                i32x4 b = Wswz[((f * 8 + ct) * 4 + kt) * 64 + l];
                asm volatile("v_mfma_f32_16x16x32_bf16 %0, %1, %2, %0"
                             : "+v"(acc[f][ct]) : "v"(a_hi[kt]), "v"(b));
                asm volatile("v_mfma_f32_16x16x32_bf16 %0, %1, %2, %0"
                             : "+v"(acc[f][ct]) : "v"(a_lo[kt]), "v"(b));
            }

    // D layout (HW-verified m89/m91): col = l&15, row = (l>>4)*4 + reg
#pragma unroll
    for (int ct = 0; ct < 8; ++ct)
#pragma unroll
        for (int f = 0; f < 2; ++f) {
            f32x4 a = acc[f][ct];
            ACC_FENCE(a);
            ushort* Hf = H + (size_t)f * BN * 128;
            size_t base = (size_t)(rbase + w * 16 + (l >> 4) * 4) * 128
                        + ct * 16 + (l & 15);
            Hf[base]       = f2bf(a.x);
            Hf[base + 128] = f2bf(a.y);
            Hf[base + 256] = f2bf(a.z);
            Hf[base + 384] = f2bf(a.w);
        }
}

// ---- fused per-bucket LDS sort + gather: out[r] = relu(sum0 + sum1) ------
__device__ __forceinline__ void fma4(float4& a, float v, ushort4 h) {
    a.x = fmaf(v, bf2f(h.x), a.x);
    a.y = fmaf(v, bf2f(h.y), a.y);
    a.z = fmaf(v, bf2f(h.z), a.z);
    a.w = fmaf(v, bf2f(h.w), a.w);
}

__global__ __launch_bounds__(512) void sort_gather(
        const uint* __restrict__ cvy, const uchar* __restrict__ cvr,
        const int* __restrict__ cur_g,
        const ushort* __restrict__ H, int BN,
        float* __restrict__ out) {
    __shared__ uint cvl[2][CAP];          // 24 KB: sorted (col|val) per filter
    __shared__ int rp[2][RPB + 1];        // per-local-row start into cvl
    __shared__ int hcnt[RPB];
    __shared__ int curs[RPB];
    __shared__ int scount[2], sovf[2];

    const int b = blockIdx.x;
    const int t = threadIdx.x;

    // ---- phase 1: sort this bucket's edges by row&127 into LDS ----
#pragma unroll 1
    for (int f = 0; f < 2; ++f) {
        if (t == 0) {
            int n0 = cur_g[f * NBK + b];
            if (n0 > GCAP) n0 = GCAP;     // matches partition's write clamp
            scount[f] = n0;
            sovf[f]   = n0 > CAP;
        }
        if (t < RPB) hcnt[t] = 0;
        __syncthreads();
        const int n = scount[f];
        const uchar* rin = cvr + (size_t)(f * NBK + b) * GCAP;
        const uint*  yin = cvy + (size_t)(f * NBK + b) * GCAP;
        for (int i = t; i < n; i += 512)
            atomicAdd(&hcnt[rin[i]], 1);
        __syncthreads();
        int v = (t < RPB) ? hcnt[t] : 0;
        if (t < RPB) curs[t] = v;
        __syncthreads();
        for (int off = 1; off < RPB; off <<= 1) {     // inclusive Hillis-Steele
            int u = 0;
            if (t < RPB && t >= off) u = curs[t - off];
            __syncthreads();
            if (t < RPB) curs[t] += u;
            __syncthreads();
        }
        if (t < RPB) {
            int ex = curs[t] - v;                     // exclusive base
            rp[f][t] = ex;
            curs[t] = ex;
        }
        if (t == 0) rp[f][RPB] = n;
        __syncthreads();
        if (!sovf[f]) {
            for (int i = t; i < n; i += 512) {
                uchar r = rin[i];
                int pos = atomicAdd(&curs[r], 1);
                cvl[f][pos] = __builtin_nontemporal_load(&yin[i]);
            }
        }
        __syncthreads();
    }

    // ---- phase 2: gather. 16 half-waves x 8 rows each ----
    const int half = t >> 5;              // 0..15
    const int sub  = t & 31;              // float4 column slot
    f32x4* outv = reinterpret_cast<f32x4*>(out);

#pragma unroll 1
    for (int k = 0; k < 8; ++k) {
        const int lr = k * 16 + half;                 // local row 0..127
        const long gr = (long)b * RPB + lr;           // global row

        float4 a0 = make_float4(0.f, 0.f, 0.f, 0.f);
        float4 a1 = make_float4(0.f, 0.f, 0.f, 0.f);
        float4 a2 = make_float4(0.f, 0.f, 0.f, 0.f);
        float4 a3 = make_float4(0.f, 0.f, 0.f, 0.f);

#pragma unroll
        for (int f = 0; f < 2; ++f) {
            const ushort* Hf = H + (size_t)f * BN * 128;
            if (!sovf[f]) {
                int e = rp[f][lr];
                const int e1 = rp[f][lr + 1];
                for (; e + 7 < e1; e += 8) {
                    uint p0 = cvl[f][e],     p1 = cvl[f][e + 1];
                    uint p2 = cvl[f][e + 2], p3 = cvl[f][e + 3];
                    uint p4 = cvl[f][e + 4], p5 = cvl[f][e + 5];
                    uint p6 = cvl[f][e + 6], p7 = cvl[f][e + 7];
                    ushort4 h0 = reinterpret_cast<const ushort4*>(Hf + (size_t)(p0 >> 16) * 128)[sub];
                    ushort4 h1 = reinterpret_cast<const ushort4*>(Hf + (size_t)(p1 >> 16) * 128)[sub];
                    ushort4 h2 = reinterpret_cast<const ushort4*>(Hf + (size_t)(p2 >> 16) * 128)[sub];
                    ushort4 h3 = reinterpret_cast<const ushort4*>(Hf + (size_t)(p3 >> 16) * 128)[sub];
                    ushort4 h4 = reinterpret_cast<const ushort4*>(Hf + (size_t)(p4 >> 16) * 128)[sub];
                    ushort4 h5 = reinterpret_cast<const ushort4*>(Hf + (size_t)(p5 >> 16) * 128)[sub];
                    ushort4 h6 = reinterpret_cast<const ushort4*>(Hf + (size_t)(p6 >> 16) * 128)[sub];
                    ushort4 h7 = reinterpret_cast<const ushort4*>(Hf + (size_t)(p7 >> 16) * 128)[sub];
                    fma4(a0, __uint_as_float(p0 << 16), h0);
                    fma4(a1, __uint_as_float(p1 << 16), h1);
                    fma4(a2, __uint_as_float(p2 << 16), h2);
                    fma4(a3, __uint_as_float(p3 << 16), h3);
                    fma4(a0, __uint_as_float(p4 << 16), h4);
                    fma4(a1, __uint_as_float(p5 << 16), h5);
                    fma4(a2, __uint_as_float(p6 << 16), h6);
                    fma4(a3, __uint_as_float(p7 << 16), h7);
                }
                for (; e + 3 < e1; e += 4) {
                    uint p0 = cvl[f][e],     p1 = cvl[f][e + 1];
                    uint p2 = cvl[f][e + 2], p3 = cvl[f][e + 3];
                    ushort4 h0 = reinterpret_cast<const ushort4*>(Hf + (size_t)(p0 >> 16) * 128)[sub];
                    ushort4 h1 = reinterpret_cast<const ushort4*>(Hf + (size_t)(p1 >> 16) * 128)[sub];
                    ushort4 h2 = reinterpret_cast<const ushort4*>(Hf + (size_t)(p2 >> 16) * 128)[sub];
                    ushort4 h3 = reinterpret_cast<const ushort4*>(Hf + (size_t)(p3 >> 16) * 128)[sub];
                    fma4(a0, __uint_as_float(p0 << 16), h0);
                    fma4(a1, __uint_as_float(p1 << 16), h1);
                    fma4(a2, __uint_as_float(p2 << 16), h2);
                    fma4(a3, __uint_as_float(p3 << 16), h3);
                }
                for (; e < e1; ++e) {
                    uint p0 = cvl[f][e];
                    ushort4 h0 = reinterpret_cast<const ushort4*>(Hf + (size_t)(p0 >> 16) * 128)[sub];
                    fma4(a0, __uint_as_float(p0 << 16), h0);
                }
            } else {
                // never-taken safety path (bucket > CAP): scan region
                const int n = scount[f];
                const uchar* rin = cvr + (size_t)(f * NBK + b) * GCAP;
                const uint*  yin = cvy + (size_t)(f * NBK + b) * GCAP;
                for (int i = 0; i < n; ++i) {
                    if (rin[i] == (uchar)lr) {
                        uint p0 = yin[i];
                        ushort4 h0 = reinterpret_cast<const ushort4*>(Hf + (size_t)(p0 >> 16) * 128)[sub];
                        fma4(a0, __uint_as_float(p0 << 16), h0);
                    }
                }
            }
        }

        f32x4 o;
        o.x = fmaxf((a0.x + a1.x) + (a2.x + a3.x), 0.0f);
        o.y = fmaxf((a0.y + a1.y) + (a2.y + a3.y), 0.0f);
        o.z = fmaxf((a0.z + a1.z) + (a2.z + a3.z), 0.0f);
        o.w = fmaxf((a0.w + a1.w) + (a2.w + a3.w), 0.0f);
        __builtin_nontemporal_store(o, outv + gr * 32 + sub);
    }
}

extern "C" void kernel_launch(void* const* d_in, const int* in_sizes, int n_in,
                              void* d_out, int out_size, void* d_ws, size_t ws_size,
                              hipStream_t stream) {
    const float* X     = (const float*)d_in[0];
    const float* W0    = (const float*)d_in[1];
    const float* W1    = (const float*)d_in[2];
    const int*   rows0 = (const int*)d_in[3];
    const int*   cols0 = (const int*)d_in[4];
    const float* vals0 = (const float*)d_in[5];
    const int*   rows1 = (const int*)d_in[6];
    const int*   cols1 = (const int*)d_in[7];
    const float* vals1 = (const float*)d_in[8];
    float* out = (float*)d_out;

    const int BN = in_sizes[0] / 128;               // 65536
    const int E  = in_sizes[3];                     // 1048576
    const int partb = (E + EPB - 1) / EPB;          // 128

    // Workspace (~51.9 MB; >= ~54.4 MB proven available in round 8):
    char* ws = (char*)d_ws;
    size_t off = 0;
    auto alloc = [&](size_t bytes) {
        void* p = ws + off;
        off = (off + bytes + 255) & ~(size_t)255;
        return p;
    };
    ushort* H     = (ushort*)alloc((size_t)2 * BN * 128 * sizeof(ushort));   // 32 MiB
    uint4*  Wswz  = (uint4*) alloc((size_t)2 * 128 * 128 * sizeof(ushort));  // 128 KiB
    uint*   cvy   = (uint*)  alloc((size_t)2 * NBK * GCAP * sizeof(uint));   // 14.7 MiB
    uchar*  cvr   = (uchar*) alloc((size_t)2 * NBK * GCAP * sizeof(uchar));  // 3.7 MiB
    int*    cur_g = (int*)   alloc((size_t)2 * NBK * sizeof(int));           // 4 KiB

    w_swz<<<65, 64, 0, stream>>>(W0, W1, Wswz, cur_g);
    gemm_part<<<2 * partb + BN / 64, 256, 0, stream>>>(
        X, (const i32x4*)Wswz, H, BN,
        rows0, cols0, vals0, rows1, cols1, vals1,
        cur_g, cvy, cvr, E, partb);
    sort_gather<<<NBK, 512, 0, stream>>>(cvy, cvr, cur_g, H, BN, out);
}